// Round 1
// baseline (77.630 us; speedup 1.0000x reference)
//
#include <hip/hip_runtime.h>

#define NB  16
#define NTQ 64
#define NTV 256
#define ND  512
#define NU  512

typedef _Float16 half8_t __attribute__((ext_vector_type(8)));
typedef float floatx4 __attribute__((ext_vector_type(4)));

__device__ __forceinline__ float wred_sum(float x) {
#pragma unroll
    for (int m = 1; m < 64; m <<= 1) x += __shfl_xor(x, m, 64);
    return x;
}
__device__ __forceinline__ float wred_max(float x) {
#pragma unroll
    for (int m = 1; m < 64; m <<= 1) x = fmaxf(x, __shfl_xor(x, m, 64));
    return x;
}

// ---------------- K1: prep (transpose W1/W2 -> f16, convert query/values -> f16, CVb = Vb + sum(Vw))
__global__ __launch_bounds__(256) void prep_kernel(
        const float* __restrict__ W1, const float* __restrict__ W2,
        const float* __restrict__ query, const float* __restrict__ values,
        const float* __restrict__ Vw, const float* __restrict__ Vb,
        _Float16* __restrict__ W1T, _Float16* __restrict__ W2T,
        _Float16* __restrict__ qh, _Float16* __restrict__ vh,
        float* __restrict__ CVb) {
    const int blk = blockIdx.x;
    const int t = threadIdx.x;
    __shared__ float tb[32][33];
    if (blk < 512) {
        // transpose 512x512: WT[u][d] = W[d][u], cast f16. 256 tiles of 32x32 per matrix.
        const float* W = (blk < 256) ? W1 : W2;
        _Float16* WT = (blk < 256) ? W1T : W2T;
        const int tile = blk & 255;
        const int tr = tile >> 4, tc = tile & 15;
        const int c = t & 31, r8 = t >> 5;
#pragma unroll
        for (int i = 0; i < 4; ++i) {
            int r = r8 + 8 * i;
            tb[r][c] = W[(tr * 32 + r) * 512 + tc * 32 + c];
        }
        __syncthreads();
#pragma unroll
        for (int i = 0; i < 4; ++i) {
            int r = r8 + 8 * i;
            WT[(tc * 32 + r) * 512 + tr * 32 + c] = (_Float16)tb[c][r];
        }
    } else if (blk < 1792) {
        // f32 -> f16 convert, 2048 elems per block
        const bool isQ = blk < 768;
        const float* src = isQ ? query : values;
        _Float16* dst = isQ ? qh : vh;
        const int base = (isQ ? (blk - 512) : (blk - 768)) * 2048 + t * 8;
        float4 f0 = *(const float4*)(src + base);
        float4 f1 = *(const float4*)(src + base + 4);
        half8_t h;
        h[0] = (_Float16)f0.x; h[1] = (_Float16)f0.y;
        h[2] = (_Float16)f0.z; h[3] = (_Float16)f0.w;
        h[4] = (_Float16)f1.x; h[5] = (_Float16)f1.y;
        h[6] = (_Float16)f1.z; h[7] = (_Float16)f1.w;
        *(half8_t*)(dst + base) = h;
    } else {
        // CVb = Vb + sum(Vw)
        float s = Vw[t] + Vw[t + 256];
        s = wred_sum(s);
        const int l = t & 63, w = t >> 6;
        __shared__ float ws4[4];
        if (l == 0) ws4[w] = s;
        __syncthreads();
        if (t == 0) CVb[0] = ws4[0] + ws4[1] + ws4[2] + ws4[3] + Vb[0];
    }
}

// ---------------- K2: fused projections, f16 MFMA, NT-GEMM (A row-major MxK, B as [N][K])
// bid < 32 : qps[m=(b,q)][u] = KC*(query@W1 + b1)          (bias per col)
// bid >= 32: vpsT[b][u][v]   = KC*(W2T@values_b^T + b2[u]) (bias per row) -- transposed v_proj
__global__ __launch_bounds__(256) void proj_gemm_kernel(
        const _Float16* __restrict__ qh, const _Float16* __restrict__ vh,
        const _Float16* __restrict__ W1T, const _Float16* __restrict__ W2T,
        const float* __restrict__ b1, const float* __restrict__ b2,
        float* __restrict__ qps, float* __restrict__ vpsT) {
    __shared__ __align__(16) _Float16 As[128 * 40];  // [row][k], pad 40 halfs
    __shared__ __align__(16) _Float16 Bs[128 * 40];  // [col][k]
    const float KC = 2.8853900817779268f;  // 2*log2(e)
    const int bid = blockIdx.x;
    const int t = threadIdx.x;
    const int l = t & 63, w = t >> 6;

    const _Float16* Ag; const _Float16* Bg;
    const float* bias; float* Cg;
    int ldc, tm, tn; bool rowBias;
    if (bid < 32) {
        tm = (bid >> 2) * 128; tn = (bid & 3) * 128;
        Ag = qh; Bg = W1T; bias = b1; Cg = qps; ldc = NU; rowBias = false;
    } else {
        const int v = bid - 32;
        const int bb = v >> 3, r = v & 7;
        tm = (r >> 1) * 128; tn = (r & 1) * 128;
        Ag = W2T; Bg = vh + bb * (NTV * ND); bias = b2;
        Cg = vpsT + bb * (NU * NTV); ldc = NTV; rowBias = true;
    }

    floatx4 acc[4][4] = {};

    const int srow = t >> 1, spart = (t & 1) * 16;
    const int wm = (w >> 1) * 64, wn = (w & 1) * 64;
    const int lr = l & 15, lk = l >> 4;

    for (int kk = 0; kk < 512; kk += 32) {
        __syncthreads();
        half8_t a0 = *(const half8_t*)(Ag + (tm + srow) * 512 + kk + spart);
        half8_t a1 = *(const half8_t*)(Ag + (tm + srow) * 512 + kk + spart + 8);
        half8_t bb0 = *(const half8_t*)(Bg + (tn + srow) * 512 + kk + spart);
        half8_t bb1 = *(const half8_t*)(Bg + (tn + srow) * 512 + kk + spart + 8);
        *(half8_t*)(As + srow * 40 + spart) = a0;
        *(half8_t*)(As + srow * 40 + spart + 8) = a1;
        *(half8_t*)(Bs + srow * 40 + spart) = bb0;
        *(half8_t*)(Bs + srow * 40 + spart + 8) = bb1;
        __syncthreads();
        half8_t af[4], bf[4];
#pragma unroll
        for (int i = 0; i < 4; ++i)
            af[i] = *(const half8_t*)(As + (wm + 16 * i + lr) * 40 + lk * 8);
#pragma unroll
        for (int j = 0; j < 4; ++j)
            bf[j] = *(const half8_t*)(Bs + (wn + 16 * j + lr) * 40 + lk * 8);
#pragma unroll
        for (int i = 0; i < 4; ++i)
#pragma unroll
            for (int j = 0; j < 4; ++j)
                acc[i][j] = __builtin_amdgcn_mfma_f32_16x16x32_f16(af[i], bf[j], acc[i][j], 0, 0, 0);
    }

    // C/D layout (verified m89/m91): col = lane&15, row = (lane>>4)*4 + reg
#pragma unroll
    for (int i = 0; i < 4; ++i) {
#pragma unroll
        for (int j = 0; j < 4; ++j) {
            const int gr0 = tm + wm + 16 * i + lk * 4;
            const int gc = tn + wn + 16 * j + lr;
#pragma unroll
            for (int r = 0; r < 4; ++r) {
                const int gr = gr0 + r;
                const float bv = rowBias ? bias[gr] : bias[gc];
                Cg[gr * ldc + gc] = KC * (acc[i][j][r] + bv);
            }
        }
    }
}

// ---------------- K3: fused score(tanh-dot) + mask + softmax + context
// thread t <-> encoder position v; no cross-lane reduction in the hot loop.
// score = CVb - 2 * sum_u Vw[u] / (1 + exp2(qps[u] + vpsT[u][v]))
__global__ __launch_bounds__(256) void score_kernel(
        const float* __restrict__ qps, const float* __restrict__ vpsT,
        const float* __restrict__ values, const int* __restrict__ enc_mask,
        const float* __restrict__ CVbp, const float* __restrict__ Vw,
        float* __restrict__ out) {
    const int bid = blockIdx.x;
    const int b = bid & 15, qp2 = bid >> 4;  // b-clustered: all blocks of batch b land on XCD b%8
    const int q0 = qp2 * 2;
    const int t = threadIdx.x;
    const int l = t & 63, w = t >> 6;

    __shared__ float rs0[4], rs1[4], ss0[4], ss1[4];
    __shared__ __align__(16) float attL[2][256];

    const float* vbp = vpsT + b * (NU * NTV);
    const float* q0p = qps + (b * NTQ + q0) * NU;
    const float* q1p = q0p + NU;

    float acc0 = 0.f, acc1 = 0.f;
    for (int u = 0; u < NU; u += 4) {
        const float4 qa = *(const float4*)(q0p + u);   // wave-uniform -> s_load
        const float4 qb = *(const float4*)(q1p + u);
        const float4 vw = *(const float4*)(Vw + u);
        const float x0 = vbp[(u + 0) * NTV + t];       // coalesced
        const float x1 = vbp[(u + 1) * NTV + t];
        const float x2 = vbp[(u + 2) * NTV + t];
        const float x3 = vbp[(u + 3) * NTV + t];
        acc0 = fmaf(vw.x, __builtin_amdgcn_rcpf(1.f + __builtin_amdgcn_exp2f(qa.x + x0)), acc0);
        acc0 = fmaf(vw.y, __builtin_amdgcn_rcpf(1.f + __builtin_amdgcn_exp2f(qa.y + x1)), acc0);
        acc0 = fmaf(vw.z, __builtin_amdgcn_rcpf(1.f + __builtin_amdgcn_exp2f(qa.z + x2)), acc0);
        acc0 = fmaf(vw.w, __builtin_amdgcn_rcpf(1.f + __builtin_amdgcn_exp2f(qa.w + x3)), acc0);
        acc1 = fmaf(vw.x, __builtin_amdgcn_rcpf(1.f + __builtin_amdgcn_exp2f(qb.x + x0)), acc1);
        acc1 = fmaf(vw.y, __builtin_amdgcn_rcpf(1.f + __builtin_amdgcn_exp2f(qb.y + x1)), acc1);
        acc1 = fmaf(vw.z, __builtin_amdgcn_rcpf(1.f + __builtin_amdgcn_exp2f(qb.z + x2)), acc1);
        acc1 = fmaf(vw.w, __builtin_amdgcn_rcpf(1.f + __builtin_amdgcn_exp2f(qb.w + x3)), acc1);
    }

    const float cvb = CVbp[0];
    float s0 = cvb - 2.f * acc0;
    float s1 = cvb - 2.f * acc1;
    const int mk = enc_mask[b * NTV + t];
    const float pen = mk ? 0.f : 1e9f;
    s0 -= pen; s1 -= pen;

    // block softmax over 256 positions
    float m0 = wred_max(s0), m1 = wred_max(s1);
    if (l == 0) { rs0[w] = m0; rs1[w] = m1; }
    __syncthreads();
    m0 = fmaxf(fmaxf(rs0[0], rs0[1]), fmaxf(rs0[2], rs0[3]));
    m1 = fmaxf(fmaxf(rs1[0], rs1[1]), fmaxf(rs1[2], rs1[3]));
    const float LOG2E = 1.4426950408889634f;
    float e0 = __builtin_amdgcn_exp2f((s0 - m0) * LOG2E);
    float e1 = __builtin_amdgcn_exp2f((s1 - m1) * LOG2E);
    float t0 = wred_sum(e0), t1 = wred_sum(e1);
    if (l == 0) { ss0[w] = t0; ss1[w] = t1; }
    __syncthreads();
    const float S0 = (ss0[0] + ss0[1]) + (ss0[2] + ss0[3]);
    const float S1 = (ss1[0] + ss1[1]) + (ss1[2] + ss1[3]);
    const float a0 = e0 * __builtin_amdgcn_rcpf(S0);
    const float a1 = e1 * __builtin_amdgcn_rcpf(S1);
    attL[0][t] = a0;
    attL[1][t] = a1;
    float* out_attn = out + NB * NTQ * ND;
    out_attn[(b * NTQ + q0) * NTV + t] = a0;
    out_attn[(b * NTQ + q0 + 1) * NTV + t] = a1;
    __syncthreads();

    // context[q][d] = sum_v attn[q][v] * values[b][v][d]; thread t owns d = 2t, 2t+1 (f32 values)
    float c00 = 0.f, c01 = 0.f, c10 = 0.f, c11 = 0.f;
    const float* vsrc = values + (b * NTV) * ND + 2 * t;
    for (int v4 = 0; v4 < 256; v4 += 4) {
        const float4 a0v = *(const float4*)(&attL[0][v4]);  // broadcast
        const float4 a1v = *(const float4*)(&attL[1][v4]);
        const float* ap0 = (const float*)&a0v;
        const float* ap1 = (const float*)&a1v;
#pragma unroll
        for (int i = 0; i < 4; ++i) {
            const float2 vv = *(const float2*)(vsrc + (v4 + i) * ND);
            c00 = fmaf(ap0[i], vv.x, c00);
            c01 = fmaf(ap0[i], vv.y, c01);
            c10 = fmaf(ap1[i], vv.x, c10);
            c11 = fmaf(ap1[i], vv.y, c11);
        }
    }
    float2* o0 = (float2*)(out + (b * NTQ + q0) * ND + 2 * t);
    float2* o1 = (float2*)(out + (b * NTQ + q0 + 1) * ND + 2 * t);
    *o0 = make_float2(c00, c01);
    *o1 = make_float2(c10, c11);
}

extern "C" void kernel_launch(void* const* d_in, const int* in_sizes, int n_in,
                              void* d_out, int out_size, void* d_ws, size_t ws_size,
                              hipStream_t stream) {
    const float* query  = (const float*)d_in[0];
    const float* values = (const float*)d_in[1];
    const int*   emask  = (const int*)d_in[2];
    const float* W1     = (const float*)d_in[3];
    const float* b1     = (const float*)d_in[4];
    const float* W2     = (const float*)d_in[5];
    const float* b2     = (const float*)d_in[6];
    const float* Vw     = (const float*)d_in[7];
    const float* Vb     = (const float*)d_in[8];
    float* out = (float*)d_out;

    char* ws = (char*)d_ws;
    _Float16* W1T = (_Float16*)(ws + 0);         //  512 KB  [U][D] f16
    _Float16* W2T = (_Float16*)(ws + 524288);    //  512 KB  [U][D] f16
    _Float16* qh  = (_Float16*)(ws + 1048576);   //    1 MB  [B*TQ][D] f16
    _Float16* vh  = (_Float16*)(ws + 2097152);   //    4 MB  [B*TV][D] f16
    float* qps    = (float*)(ws + 6291456);      //    2 MB  [B*TQ][U] f32 (scaled)
    float* vpsT   = (float*)(ws + 8388608);      //    8 MB  [B][U][TV] f32 (scaled, transposed)
    float* CVb    = (float*)(ws + 16777216);     //    4 B

    prep_kernel<<<dim3(1793), dim3(256), 0, stream>>>(W1, W2, query, values, Vw, Vb,
                                                      W1T, W2T, qh, vh, CVb);
    proj_gemm_kernel<<<dim3(160), dim3(256), 0, stream>>>(qh, vh, W1T, W2T, b1, b2, qps, vpsT);
    score_kernel<<<dim3(512), dim3(256), 0, stream>>>(qps, vpsT, values, emask, CVb, Vw, out);
}

// Round 2
// 76.330 us; speedup vs baseline: 1.0170x; 1.0170x over previous
//
#include <hip/hip_runtime.h>

#define NB  16
#define NTQ 64
#define NTV 256
#define ND  512
#define NU  512

typedef _Float16 half8_t __attribute__((ext_vector_type(8)));
typedef float floatx4 __attribute__((ext_vector_type(4)));

__device__ __forceinline__ float wred_sum(float x) {
#pragma unroll
    for (int m = 1; m < 64; m <<= 1) x += __shfl_xor(x, m, 64);
    return x;
}
__device__ __forceinline__ float wred_max(float x) {
#pragma unroll
    for (int m = 1; m < 64; m <<= 1) x = fmaxf(x, __shfl_xor(x, m, 64));
    return x;
}

// ---------------- K1: prep (transpose W1/W2 -> f16, convert query/values -> f16, CVb = Vb + sum(Vw))
__global__ __launch_bounds__(256) void prep_kernel(
        const float* __restrict__ W1, const float* __restrict__ W2,
        const float* __restrict__ query, const float* __restrict__ values,
        const float* __restrict__ Vw, const float* __restrict__ Vb,
        _Float16* __restrict__ W1T, _Float16* __restrict__ W2T,
        _Float16* __restrict__ qh, _Float16* __restrict__ vh,
        float* __restrict__ CVb) {
    const int blk = blockIdx.x;
    const int t = threadIdx.x;
    __shared__ float tb[32][33];
    if (blk < 512) {
        // transpose 512x512: WT[u][d] = W[d][u], cast f16. 256 tiles of 32x32 per matrix.
        const float* W = (blk < 256) ? W1 : W2;
        _Float16* WT = (blk < 256) ? W1T : W2T;
        const int tile = blk & 255;
        const int tr = tile >> 4, tc = tile & 15;
        const int c = t & 31, r8 = t >> 5;
#pragma unroll
        for (int i = 0; i < 4; ++i) {
            int r = r8 + 8 * i;
            tb[r][c] = W[(tr * 32 + r) * 512 + tc * 32 + c];
        }
        __syncthreads();
#pragma unroll
        for (int i = 0; i < 4; ++i) {
            int r = r8 + 8 * i;
            WT[(tc * 32 + r) * 512 + tr * 32 + c] = (_Float16)tb[c][r];
        }
    } else if (blk < 1792) {
        // f32 -> f16 convert, 2048 elems per block
        const bool isQ = blk < 768;
        const float* src = isQ ? query : values;
        _Float16* dst = isQ ? qh : vh;
        const int base = (isQ ? (blk - 512) : (blk - 768)) * 2048 + t * 8;
        float4 f0 = *(const float4*)(src + base);
        float4 f1 = *(const float4*)(src + base + 4);
        half8_t h;
        h[0] = (_Float16)f0.x; h[1] = (_Float16)f0.y;
        h[2] = (_Float16)f0.z; h[3] = (_Float16)f0.w;
        h[4] = (_Float16)f1.x; h[5] = (_Float16)f1.y;
        h[6] = (_Float16)f1.z; h[7] = (_Float16)f1.w;
        *(half8_t*)(dst + base) = h;
    } else {
        // CVb = Vb + sum(Vw)
        float s = Vw[t] + Vw[t + 256];
        s = wred_sum(s);
        const int l = t & 63, w = t >> 6;
        __shared__ float ws4[4];
        if (l == 0) ws4[w] = s;
        __syncthreads();
        if (t == 0) CVb[0] = ws4[0] + ws4[1] + ws4[2] + ws4[3] + Vb[0];
    }
}

// ---------------- K2: fused projections, f16 MFMA, NT-GEMM (A row-major MxK, B as [N][K])
// bid < 32 : qps[m=(b,q)][u] = KC*(query@W1 + b1)          (bias per col)
// bid >= 32: vpsT[b][u][v]   = KC*(W2T@values_b^T + b2[u]) (bias per row) -- transposed v_proj
__global__ __launch_bounds__(256) void proj_gemm_kernel(
        const _Float16* __restrict__ qh, const _Float16* __restrict__ vh,
        const _Float16* __restrict__ W1T, const _Float16* __restrict__ W2T,
        const float* __restrict__ b1, const float* __restrict__ b2,
        float* __restrict__ qps, float* __restrict__ vpsT) {
    __shared__ __align__(16) _Float16 As[128 * 40];  // [row][k], pad 40 halfs
    __shared__ __align__(16) _Float16 Bs[128 * 40];  // [col][k]
    const float KC = 2.8853900817779268f;  // 2*log2(e)
    const int bid = blockIdx.x;
    const int t = threadIdx.x;
    const int l = t & 63, w = t >> 6;

    const _Float16* Ag; const _Float16* Bg;
    const float* bias; float* Cg;
    int ldc, tm, tn; bool rowBias;
    if (bid < 32) {
        tm = (bid >> 2) * 128; tn = (bid & 3) * 128;
        Ag = qh; Bg = W1T; bias = b1; Cg = qps; ldc = NU; rowBias = false;
    } else {
        const int v = bid - 32;
        const int bb = v >> 3, r = v & 7;
        tm = (r >> 1) * 128; tn = (r & 1) * 128;
        Ag = W2T; Bg = vh + bb * (NTV * ND); bias = b2;
        Cg = vpsT + bb * (NU * NTV); ldc = NTV; rowBias = true;
    }

    floatx4 acc[4][4] = {};

    const int srow = t >> 1, spart = (t & 1) * 16;
    const int wm = (w >> 1) * 64, wn = (w & 1) * 64;
    const int lr = l & 15, lk = l >> 4;

    for (int kk = 0; kk < 512; kk += 32) {
        __syncthreads();
        half8_t a0 = *(const half8_t*)(Ag + (tm + srow) * 512 + kk + spart);
        half8_t a1 = *(const half8_t*)(Ag + (tm + srow) * 512 + kk + spart + 8);
        half8_t bb0 = *(const half8_t*)(Bg + (tn + srow) * 512 + kk + spart);
        half8_t bb1 = *(const half8_t*)(Bg + (tn + srow) * 512 + kk + spart + 8);
        *(half8_t*)(As + srow * 40 + spart) = a0;
        *(half8_t*)(As + srow * 40 + spart + 8) = a1;
        *(half8_t*)(Bs + srow * 40 + spart) = bb0;
        *(half8_t*)(Bs + srow * 40 + spart + 8) = bb1;
        __syncthreads();
        half8_t af[4], bf[4];
#pragma unroll
        for (int i = 0; i < 4; ++i)
            af[i] = *(const half8_t*)(As + (wm + 16 * i + lr) * 40 + lk * 8);
#pragma unroll
        for (int j = 0; j < 4; ++j)
            bf[j] = *(const half8_t*)(Bs + (wn + 16 * j + lr) * 40 + lk * 8);
#pragma unroll
        for (int i = 0; i < 4; ++i)
#pragma unroll
            for (int j = 0; j < 4; ++j)
                acc[i][j] = __builtin_amdgcn_mfma_f32_16x16x32_f16(af[i], bf[j], acc[i][j], 0, 0, 0);
    }

    // C/D layout (verified m89/m91): col = lane&15, row = (lane>>4)*4 + reg
#pragma unroll
    for (int i = 0; i < 4; ++i) {
#pragma unroll
        for (int j = 0; j < 4; ++j) {
            const int gr0 = tm + wm + 16 * i + lk * 4;
            const int gc = tn + wn + 16 * j + lr;
#pragma unroll
            for (int r = 0; r < 4; ++r) {
                const int gr = gr0 + r;
                const float bv = rowBias ? bias[gr] : bias[gc];
                Cg[gr * ldc + gc] = KC * (acc[i][j][r] + bv);
            }
        }
    }
}

// ---------------- K3: fused score(tanh-dot) + mask + softmax + context
// 1024 threads: score phase splits U 4-ways (ug = t>>8, v = t&255) -> 16 waves/block,
// 2 blocks/CU -> 100% occupancy ceiling (R0 was latency-bound at 16%).
// score = CVb - 2 * sum_u Vw[u] / (1 + exp2(qps[u] + vpsT[u][v]))
__global__ __launch_bounds__(1024) void score_kernel(
        const float* __restrict__ qps, const float* __restrict__ vpsT,
        const float* __restrict__ values, const int* __restrict__ enc_mask,
        const float* __restrict__ CVbp, const float* __restrict__ Vw,
        float* __restrict__ out) {
    const int bid = blockIdx.x;
    const int b = bid & 15, qp2 = bid >> 4;  // b-clustered: all blocks of batch b land on XCD b%8
    const int q0 = qp2 * 2;
    const int t = threadIdx.x;
    const int l = t & 63, w = t >> 6;       // w in 0..15
    const int ug = t >> 8;                  // u-group 0..3
    const int v = t & 255;

    __shared__ float pacc[2][4][256];       // [q][ug][v]  8 KB
    __shared__ float attL[2][256];
    __shared__ float rs0[4], rs1[4], ss0[4], ss1[4];

    const float* vbp = vpsT + b * (NU * NTV);
    const float* q0p = qps + (b * NTQ + q0) * NU;
    const float* q1p = q0p + NU;

    float acc0 = 0.f, acc1 = 0.f;
    const int ub = ug * 128;
    for (int u = ub; u < ub + 128; u += 4) {
        const float4 qa = *(const float4*)(q0p + u);   // wave-uniform -> s_load
        const float4 qb = *(const float4*)(q1p + u);
        const float4 vw = *(const float4*)(Vw + u);
        const float x0 = vbp[(u + 0) * NTV + v];       // coalesced, L2-resident
        const float x1 = vbp[(u + 1) * NTV + v];
        const float x2 = vbp[(u + 2) * NTV + v];
        const float x3 = vbp[(u + 3) * NTV + v];
        acc0 = fmaf(vw.x, __builtin_amdgcn_rcpf(1.f + __builtin_amdgcn_exp2f(qa.x + x0)), acc0);
        acc0 = fmaf(vw.y, __builtin_amdgcn_rcpf(1.f + __builtin_amdgcn_exp2f(qa.y + x1)), acc0);
        acc0 = fmaf(vw.z, __builtin_amdgcn_rcpf(1.f + __builtin_amdgcn_exp2f(qa.z + x2)), acc0);
        acc0 = fmaf(vw.w, __builtin_amdgcn_rcpf(1.f + __builtin_amdgcn_exp2f(qa.w + x3)), acc0);
        acc1 = fmaf(vw.x, __builtin_amdgcn_rcpf(1.f + __builtin_amdgcn_exp2f(qb.x + x0)), acc1);
        acc1 = fmaf(vw.y, __builtin_amdgcn_rcpf(1.f + __builtin_amdgcn_exp2f(qb.y + x1)), acc1);
        acc1 = fmaf(vw.z, __builtin_amdgcn_rcpf(1.f + __builtin_amdgcn_exp2f(qb.z + x2)), acc1);
        acc1 = fmaf(vw.w, __builtin_amdgcn_rcpf(1.f + __builtin_amdgcn_exp2f(qb.w + x3)), acc1);
    }
    pacc[0][ug][v] = acc0;
    pacc[1][ug][v] = acc1;
    __syncthreads();

    // softmax over 256 positions (waves 0..3 only; __shfl stays wave-local)
    float e0 = 0.f, e1 = 0.f, m0 = 0.f, m1 = 0.f, s0 = 0.f, s1 = 0.f;
    if (t < 256) {
        const float cvb = CVbp[0];
        s0 = (pacc[0][0][t] + pacc[0][1][t]) + (pacc[0][2][t] + pacc[0][3][t]);
        s1 = (pacc[1][0][t] + pacc[1][1][t]) + (pacc[1][2][t] + pacc[1][3][t]);
        s0 = cvb - 2.f * s0;
        s1 = cvb - 2.f * s1;
        const int mk = enc_mask[b * NTV + t];
        const float pen = mk ? 0.f : 1e9f;
        s0 -= pen; s1 -= pen;
        m0 = wred_max(s0); m1 = wred_max(s1);
        if (l == 0) { rs0[w] = m0; rs1[w] = m1; }
    }
    __syncthreads();
    if (t < 256) {
        m0 = fmaxf(fmaxf(rs0[0], rs0[1]), fmaxf(rs0[2], rs0[3]));
        m1 = fmaxf(fmaxf(rs1[0], rs1[1]), fmaxf(rs1[2], rs1[3]));
        const float LOG2E = 1.4426950408889634f;
        e0 = __builtin_amdgcn_exp2f((s0 - m0) * LOG2E);
        e1 = __builtin_amdgcn_exp2f((s1 - m1) * LOG2E);
        float t0 = wred_sum(e0), t1 = wred_sum(e1);
        if (l == 0) { ss0[w] = t0; ss1[w] = t1; }
    }
    __syncthreads();
    if (t < 256) {
        const float S0 = (ss0[0] + ss0[1]) + (ss0[2] + ss0[3]);
        const float S1 = (ss1[0] + ss1[1]) + (ss1[2] + ss1[3]);
        const float a0 = e0 * __builtin_amdgcn_rcpf(S0);
        const float a1 = e1 * __builtin_amdgcn_rcpf(S1);
        attL[0][t] = a0;
        attL[1][t] = a1;
        float* out_attn = out + NB * NTQ * ND;
        out_attn[(b * NTQ + q0) * NTV + t] = a0;
        out_attn[(b * NTQ + q0 + 1) * NTV + t] = a1;
    }
    __syncthreads();

    // context[q][d] = sum_v attn[q][v] * values[b][v][d]; 1024 threads, one (q,d) each
    const int cq = t >> 9;          // 0..1
    const int d = t & 511;
    const float* vsrc = values + b * NTV * ND + d;
    const float* aL = attL[cq];
    float cA = 0.f, cB = 0.f, cC = 0.f, cD = 0.f;
    for (int v4 = 0; v4 < 256; v4 += 4) {
        cA = fmaf(aL[v4 + 0], vsrc[(v4 + 0) * ND], cA);  // aL: LDS broadcast
        cB = fmaf(aL[v4 + 1], vsrc[(v4 + 1) * ND], cB);
        cC = fmaf(aL[v4 + 2], vsrc[(v4 + 2) * ND], cC);
        cD = fmaf(aL[v4 + 3], vsrc[(v4 + 3) * ND], cD);
    }
    out[(b * NTQ + q0 + cq) * ND + d] = (cA + cB) + (cC + cD);
}

extern "C" void kernel_launch(void* const* d_in, const int* in_sizes, int n_in,
                              void* d_out, int out_size, void* d_ws, size_t ws_size,
                              hipStream_t stream) {
    const float* query  = (const float*)d_in[0];
    const float* values = (const float*)d_in[1];
    const int*   emask  = (const int*)d_in[2];
    const float* W1     = (const float*)d_in[3];
    const float* b1     = (const float*)d_in[4];
    const float* W2     = (const float*)d_in[5];
    const float* b2     = (const float*)d_in[6];
    const float* Vw     = (const float*)d_in[7];
    const float* Vb     = (const float*)d_in[8];
    float* out = (float*)d_out;

    char* ws = (char*)d_ws;
    _Float16* W1T = (_Float16*)(ws + 0);         //  512 KB  [U][D] f16
    _Float16* W2T = (_Float16*)(ws + 524288);    //  512 KB  [U][D] f16
    _Float16* qh  = (_Float16*)(ws + 1048576);   //    1 MB  [B*TQ][D] f16
    _Float16* vh  = (_Float16*)(ws + 2097152);   //    4 MB  [B*TV][D] f16
    float* qps    = (float*)(ws + 6291456);      //    2 MB  [B*TQ][U] f32 (scaled)
    float* vpsT   = (float*)(ws + 8388608);      //    8 MB  [B][U][TV] f32 (scaled, transposed)
    float* CVb    = (float*)(ws + 16777216);     //    4 B

    prep_kernel<<<dim3(1793), dim3(256), 0, stream>>>(W1, W2, query, values, Vw, Vb,
                                                      W1T, W2T, qh, vh, CVb);
    proj_gemm_kernel<<<dim3(160), dim3(256), 0, stream>>>(qh, vh, W1T, W2T, b1, b2, qps, vpsT);
    score_kernel<<<dim3(512), dim3(1024), 0, stream>>>(qps, vpsT, values, emask, CVb, Vw, out);
}

// Round 3
// 55.529 us; speedup vs baseline: 1.3980x; 1.3746x over previous
//
#include <hip/hip_runtime.h>

#define NB  16
#define NTQ 64
#define NTV 256
#define ND  512
#define NU  512

typedef _Float16 half8_t __attribute__((ext_vector_type(8)));
typedef float floatx4 __attribute__((ext_vector_type(4)));

__device__ __forceinline__ float wred_sum(float x) {
#pragma unroll
    for (int m = 1; m < 64; m <<= 1) x += __shfl_xor(x, m, 64);
    return x;
}
__device__ __forceinline__ float wred_max(float x) {
#pragma unroll
    for (int m = 1; m < 64; m <<= 1) x = fmaxf(x, __shfl_xor(x, m, 64));
    return x;
}

// ---------------- K1: prep (transpose W1/W2 -> f16, convert query/values -> f16, CVb = Vb + sum(Vw))
__global__ __launch_bounds__(256) void prep_kernel(
        const float* __restrict__ W1, const float* __restrict__ W2,
        const float* __restrict__ query, const float* __restrict__ values,
        const float* __restrict__ Vw, const float* __restrict__ Vb,
        _Float16* __restrict__ W1T, _Float16* __restrict__ W2T,
        _Float16* __restrict__ qh, _Float16* __restrict__ vh,
        float* __restrict__ CVb) {
    const int blk = blockIdx.x;
    const int t = threadIdx.x;
    __shared__ float tb[32][33];
    if (blk < 512) {
        const float* W = (blk < 256) ? W1 : W2;
        _Float16* WT = (blk < 256) ? W1T : W2T;
        const int tile = blk & 255;
        const int tr = tile >> 4, tc = tile & 15;
        const int c = t & 31, r8 = t >> 5;
#pragma unroll
        for (int i = 0; i < 4; ++i) {
            int r = r8 + 8 * i;
            tb[r][c] = W[(tr * 32 + r) * 512 + tc * 32 + c];
        }
        __syncthreads();
#pragma unroll
        for (int i = 0; i < 4; ++i) {
            int r = r8 + 8 * i;
            WT[(tc * 32 + r) * 512 + tr * 32 + c] = (_Float16)tb[c][r];
        }
    } else if (blk < 1792) {
        const bool isQ = blk < 768;
        const float* src = isQ ? query : values;
        _Float16* dst = isQ ? qh : vh;
        const int base = (isQ ? (blk - 512) : (blk - 768)) * 2048 + t * 8;
        float4 f0 = *(const float4*)(src + base);
        float4 f1 = *(const float4*)(src + base + 4);
        half8_t h;
        h[0] = (_Float16)f0.x; h[1] = (_Float16)f0.y;
        h[2] = (_Float16)f0.z; h[3] = (_Float16)f0.w;
        h[4] = (_Float16)f1.x; h[5] = (_Float16)f1.y;
        h[6] = (_Float16)f1.z; h[7] = (_Float16)f1.w;
        *(half8_t*)(dst + base) = h;
    } else {
        float s = Vw[t] + Vw[t + 256];
        s = wred_sum(s);
        const int l = t & 63, w = t >> 6;
        __shared__ float ws4[4];
        if (l == 0) ws4[w] = s;
        __syncthreads();
        if (t == 0) CVb[0] = ws4[0] + ws4[1] + ws4[2] + ws4[3] + Vb[0];
    }
}

// ---------------- K2: fused projections, f16 MFMA; epilogue writes EXP2 of scaled proj:
// bid < 32 : Eq[m=(b,q)][u]  = exp2(KC*(query@W1 + b1))
// bid >= 32: Ev[b][u][v]     = exp2(KC*(W2T@values_b^T + b2[u]))   (transposed v_proj)
// so that e^{2(q_proj+v_proj)} = Eq * Ev  (KC = 2*log2 e)
__global__ __launch_bounds__(256) void proj_gemm_kernel(
        const _Float16* __restrict__ qh, const _Float16* __restrict__ vh,
        const _Float16* __restrict__ W1T, const _Float16* __restrict__ W2T,
        const float* __restrict__ b1, const float* __restrict__ b2,
        float* __restrict__ Eq, float* __restrict__ Ev) {
    __shared__ __align__(16) _Float16 As[128 * 40];
    __shared__ __align__(16) _Float16 Bs[128 * 40];
    const float KC = 2.8853900817779268f;  // 2*log2(e)
    const int bid = blockIdx.x;
    const int t = threadIdx.x;
    const int l = t & 63, w = t >> 6;

    const _Float16* Ag; const _Float16* Bg;
    const float* bias; float* Cg;
    int ldc, tm, tn; bool rowBias;
    if (bid < 32) {
        tm = (bid >> 2) * 128; tn = (bid & 3) * 128;
        Ag = qh; Bg = W1T; bias = b1; Cg = Eq; ldc = NU; rowBias = false;
    } else {
        const int v = bid - 32;
        const int bb = v >> 3, r = v & 7;
        tm = (r >> 1) * 128; tn = (r & 1) * 128;
        Ag = W2T; Bg = vh + bb * (NTV * ND); bias = b2;
        Cg = Ev + bb * (NU * NTV); ldc = NTV; rowBias = true;
    }

    floatx4 acc[4][4] = {};

    const int srow = t >> 1, spart = (t & 1) * 16;
    const int wm = (w >> 1) * 64, wn = (w & 1) * 64;
    const int lr = l & 15, lk = l >> 4;

    for (int kk = 0; kk < 512; kk += 32) {
        __syncthreads();
        half8_t a0 = *(const half8_t*)(Ag + (tm + srow) * 512 + kk + spart);
        half8_t a1 = *(const half8_t*)(Ag + (tm + srow) * 512 + kk + spart + 8);
        half8_t bb0 = *(const half8_t*)(Bg + (tn + srow) * 512 + kk + spart);
        half8_t bb1 = *(const half8_t*)(Bg + (tn + srow) * 512 + kk + spart + 8);
        *(half8_t*)(As + srow * 40 + spart) = a0;
        *(half8_t*)(As + srow * 40 + spart + 8) = a1;
        *(half8_t*)(Bs + srow * 40 + spart) = bb0;
        *(half8_t*)(Bs + srow * 40 + spart + 8) = bb1;
        __syncthreads();
        half8_t af[4], bf[4];
#pragma unroll
        for (int i = 0; i < 4; ++i)
            af[i] = *(const half8_t*)(As + (wm + 16 * i + lr) * 40 + lk * 8);
#pragma unroll
        for (int j = 0; j < 4; ++j)
            bf[j] = *(const half8_t*)(Bs + (wn + 16 * j + lr) * 40 + lk * 8);
#pragma unroll
        for (int i = 0; i < 4; ++i)
#pragma unroll
            for (int j = 0; j < 4; ++j)
                acc[i][j] = __builtin_amdgcn_mfma_f32_16x16x32_f16(af[i], bf[j], acc[i][j], 0, 0, 0);
    }

    // C/D layout: col = lane&15, row = (lane>>4)*4 + reg
#pragma unroll
    for (int i = 0; i < 4; ++i) {
#pragma unroll
        for (int j = 0; j < 4; ++j) {
            const int gr0 = tm + wm + 16 * i + lk * 4;
            const int gc = tn + wn + 16 * j + lr;
#pragma unroll
            for (int r = 0; r < 4; ++r) {
                const int gr = gr0 + r;
                const float bv = rowBias ? bias[gr] : bias[gc];
                Cg[gr * ldc + gc] = __builtin_amdgcn_exp2f(KC * (acc[i][j][r] + bv));
            }
        }
    }
}

// ---------------- K3: fused score + mask + softmax + context
// score = CVb - 2 * sum_u Vw[u] / (1 + Eq[u]*Ev[u][v])     (1 trans/element)
// score phase : 1024 thr = (ug 0..15) x (vq 0..63), Ev loads dwordx4
// context     : 1024 thr = (vg 0..7) x (dq 0..127), values loads dwordx4, both q's
__global__ __launch_bounds__(1024) void score_kernel(
        const float* __restrict__ Eq, const float* __restrict__ Ev,
        const float* __restrict__ values, const int* __restrict__ enc_mask,
        const float* __restrict__ CVbp, const float* __restrict__ Vw,
        float* __restrict__ out) {
    const int bid = blockIdx.x;
    const int b = bid & 15, qp2 = bid >> 4;  // blocks of batch b -> same XCD (b%8)
    const int q0 = qp2 * 2;
    const int t = threadIdx.x;

    __shared__ float pacc[2][16][256];   // 32 KB
    __shared__ float attL[2][256];       //  2 KB
    __shared__ float ctxp[2][8][520];    // 33 KB
    __shared__ float rs[2][4], ss[2][4];

    const float* evb = Ev + b * (NU * NTV);
    const float* q0p = Eq + (b * NTQ + q0) * NU;
    const float* q1p = q0p + NU;

    // ---- score phase
    {
        const int ug = t >> 6;           // wave-uniform -> scalar q/Vw loads
        const int vq = t & 63;
        floatx4 a0 = {0.f, 0.f, 0.f, 0.f}, a1 = {0.f, 0.f, 0.f, 0.f};
        const int ub = ug * 32;
#pragma unroll 4
        for (int u = ub; u < ub + 32; ++u) {
            const float eq0 = q0p[u];
            const float eq1 = q1p[u];
            const float vw = Vw[u];
            const floatx4 ev = *(const floatx4*)(evb + u * NTV + vq * 4);
#pragma unroll
            for (int j = 0; j < 4; ++j) {
                a0[j] = fmaf(vw, __builtin_amdgcn_rcpf(fmaf(eq0, ev[j], 1.f)), a0[j]);
                a1[j] = fmaf(vw, __builtin_amdgcn_rcpf(fmaf(eq1, ev[j], 1.f)), a1[j]);
            }
        }
        *(floatx4*)&pacc[0][ug][vq * 4] = a0;
        *(floatx4*)&pacc[1][ug][vq * 4] = a1;
    }
    __syncthreads();

    // ---- softmax (t < 512: q = t>>8, v = t&255; 4 waves per q)
    float sc = 0.f, ee = 0.f;
    const int q = t >> 8, v = t & 255;
    const int l = t & 63, w4 = (t >> 6) & 3;
    if (t < 512) {
        float s = 0.f;
#pragma unroll
        for (int g = 0; g < 16; ++g) s += pacc[q][g][v];
        sc = CVbp[0] - 2.f * s;
        sc -= enc_mask[b * NTV + v] ? 0.f : 1e9f;
        float m = wred_max(sc);
        if (l == 0) rs[q][w4] = m;
    }
    __syncthreads();
    if (t < 512) {
        const float m = fmaxf(fmaxf(rs[q][0], rs[q][1]), fmaxf(rs[q][2], rs[q][3]));
        const float LOG2E = 1.4426950408889634f;
        ee = __builtin_amdgcn_exp2f((sc - m) * LOG2E);
        float t0 = wred_sum(ee);
        if (l == 0) ss[q][w4] = t0;
    }
    __syncthreads();
    if (t < 512) {
        const float S = (ss[q][0] + ss[q][1]) + (ss[q][2] + ss[q][3]);
        const float a = ee * __builtin_amdgcn_rcpf(S);
        attL[q][v] = a;
        float* out_attn = out + NB * NTQ * ND;
        out_attn[(b * NTQ + q0 + q) * NTV + v] = a;
    }
    __syncthreads();

    // ---- context: thread = (vg, dq), both q's; dwordx4 values loads
    {
        const int vg = t >> 7;           // 0..7
        const int dq = t & 127;          // d = dq*4..+3
        const float* vsrc = values + (b * NTV + vg * 32) * ND + dq * 4;
        floatx4 c0 = {0.f, 0.f, 0.f, 0.f}, c1 = {0.f, 0.f, 0.f, 0.f};
#pragma unroll 4
        for (int vi = 0; vi < 32; ++vi) {
            const floatx4 vv = *(const floatx4*)(vsrc + vi * ND);
            const float w0 = attL[0][vg * 32 + vi];
            const float w1 = attL[1][vg * 32 + vi];
#pragma unroll
            for (int j = 0; j < 4; ++j) {
                c0[j] = fmaf(w0, vv[j], c0[j]);
                c1[j] = fmaf(w1, vv[j], c1[j]);
            }
        }
        *(floatx4*)&ctxp[0][vg][dq * 4] = c0;
        *(floatx4*)&ctxp[1][vg][dq * 4] = c1;
    }
    __syncthreads();
    {
        const int cq = t >> 9, d = t & 511;
        float s = 0.f;
#pragma unroll
        for (int g = 0; g < 8; ++g) s += ctxp[cq][g][d];
        out[(b * NTQ + q0 + cq) * ND + d] = s;
    }
}

extern "C" void kernel_launch(void* const* d_in, const int* in_sizes, int n_in,
                              void* d_out, int out_size, void* d_ws, size_t ws_size,
                              hipStream_t stream) {
    const float* query  = (const float*)d_in[0];
    const float* values = (const float*)d_in[1];
    const int*   emask  = (const int*)d_in[2];
    const float* W1     = (const float*)d_in[3];
    const float* b1     = (const float*)d_in[4];
    const float* W2     = (const float*)d_in[5];
    const float* b2     = (const float*)d_in[6];
    const float* Vw     = (const float*)d_in[7];
    const float* Vb     = (const float*)d_in[8];
    float* out = (float*)d_out;

    char* ws = (char*)d_ws;
    _Float16* W1T = (_Float16*)(ws + 0);         //  512 KB  [U][D] f16
    _Float16* W2T = (_Float16*)(ws + 524288);    //  512 KB  [U][D] f16
    _Float16* qh  = (_Float16*)(ws + 1048576);   //    1 MB  [B*TQ][D] f16
    _Float16* vh  = (_Float16*)(ws + 2097152);   //    4 MB  [B*TV][D] f16
    float* Eq     = (float*)(ws + 6291456);      //    2 MB  [B*TQ][U] f32 exp2-scaled
    float* Ev     = (float*)(ws + 8388608);      //    8 MB  [B][U][TV] f32 exp2-scaled
    float* CVb    = (float*)(ws + 16777216);     //    4 B

    prep_kernel<<<dim3(1793), dim3(256), 0, stream>>>(W1, W2, query, values, Vw, Vb,
                                                      W1T, W2T, qh, vh, CVb);
    proj_gemm_kernel<<<dim3(160), dim3(256), 0, stream>>>(qh, vh, W1T, W2T, b1, b2, Eq, Ev);
    score_kernel<<<dim3(512), dim3(1024), 0, stream>>>(Eq, Ev, values, emask, CVb, Vw, out);
}